// Round 4
// baseline (272.935 us; speedup 1.0000x reference)
//
#include <hip/hip_runtime.h>

// y[b, n*DOUT+o] = sum_i x[b,n,i] * W[n,i,o] + bias[n,o]
// B=2048, N=64, DIN=512, DOUT=512, fp32 in/out, bf16 MFMA (fp32 accum).
// R4: ring-3 LDS pipeline with counted vmcnt across raw barriers (T3/T4),
// BOTH operands via global_load_lds (A staged as raw fp32, cvt at frag read),
// fully unrolled K-loop. BM=64, BN=256, BK=32, 4 waves.

#define NN 64
#define DIN 512
#define DOUT 512
#define BM 64
#define BN 256
#define BK 32
#define KSTEPS (DIN / BK)         // 16
#define ROWSTRIDE (NN * DIN)
#define OUTSTRIDE (NN * DOUT)

typedef __bf16 bf16x8 __attribute__((ext_vector_type(8)));
typedef float f32x4 __attribute__((ext_vector_type(4)));
typedef unsigned int u32x4 __attribute__((ext_vector_type(4)));

__device__ __forceinline__ unsigned short f2bf(float f) {
    return __builtin_bit_cast(unsigned short, (__bf16)f);  // RNE
}
__device__ __forceinline__ unsigned int f2bf2(float a, float b) {
    return (unsigned int)f2bf(a) | ((unsigned int)f2bf(b) << 16);
}

typedef const __attribute__((address_space(1))) unsigned int* gas1_t;
typedef __attribute__((address_space(3))) unsigned int* las3_t;
__device__ __forceinline__ void gload_lds16(const void* g, void* l) {
    // LDS dest = wave-uniform base + lane*16 (m104); global src per-lane.
    __builtin_amdgcn_global_load_lds((gas1_t)g, (las3_t)l, 16, 0, 0);
}

// ---- pre-pass: Wt[n][o][i] = bf16(W[n][i][o]) ----
__global__ void wt_transpose_kernel(const float* __restrict__ W,
                                    unsigned short* __restrict__ Wt) {
    __shared__ float tile[32][33];
    const int n  = blockIdx.z;
    const int i0 = blockIdx.x * 32;
    const int o0 = blockIdx.y * 32;
    const float* Wn = W + (size_t)n * DIN * DOUT;
    unsigned short* Wtn = Wt + (size_t)n * DIN * DOUT;
    const int tx = threadIdx.x, ty = threadIdx.y;
#pragma unroll
    for (int q = 0; q < 4; ++q)
        tile[ty + q * 8][tx] = Wn[(size_t)(i0 + ty + q * 8) * DOUT + (o0 + tx)];
    __syncthreads();
#pragma unroll
    for (int q = 0; q < 4; ++q)
        Wtn[(size_t)(o0 + ty + q * 8) * DIN + (i0 + tx)] = f2bf(tile[tx][ty + q * 8]);
}

// ---- main GEMM ----
__global__ __launch_bounds__(256) void node_gemm_kernel(
    const float* __restrict__ X, const unsigned short* __restrict__ Wt,
    const float* __restrict__ Bias, float* __restrict__ Out) {
    // ring of 3 K-tiles; A stored as fp32 (slot-swizzled), B bf16 (slot-swizzled)
    __shared__ float          As[3][BM * BK];   // 3 x 8 KB
    __shared__ unsigned short Bs[3][BN * BK];   // 3 x 16 KB

    // 4096 WGs, bijective XCD swizzle (4096 % 8 == 0)
    const int bid = blockIdx.x;
    const int swz = (bid & 7) * 512 + (bid >> 3);
    const int node  = swz >> 6;
    const int rem   = swz & 63;
    const int mtile = rem >> 1;
    const int ntile = rem & 1;
    const int brow = mtile * BM;
    const int bcol = ntile * BN;

    const int tid  = threadIdx.x;
    const int lane = tid & 63;
    const int w    = tid >> 6;        // wave 0..3, owns cols 64w..64w+63

    const float* Xb = X + (size_t)brow * ROWSTRIDE + node * DIN;
    const unsigned short* Wb = Wt + (size_t)node * DIN * DOUT + (size_t)bcol * DIN;

    // ---- staging address precompute (per-lane global srcs, wave-uniform LDS bases)
    // A: 512 x 16B chunks; chunk c=(q*4+w)*64+lane -> row=c>>3, slot=c&7,
    //    LDS(row,slot) holds global kslot = slot ^ (row&7)  [bank-spread swizzle]
    const float* asrc[2];
#pragma unroll
    for (int q = 0; q < 2; ++q) {
        const int c = (q * 4 + w) * 64 + lane;
        const int row = c >> 3, slot = c & 7;
        const int gslot = slot ^ (row & 7);
        asrc[q] = Xb + (size_t)row * ROWSTRIDE + gslot * 4;
    }
    // B: 1024 x 16B chunks; chunk c=(q*4+w)*64+lane -> row=c>>2, slot=c&3,
    //    LDS(row,slot) holds global kslot = slot ^ ((row>>1)&3)
    const unsigned short* bsrc[4];
#pragma unroll
    for (int q = 0; q < 4; ++q) {
        const int c = (q * 4 + w) * 64 + lane;
        const int row = c >> 2, slot = c & 3;
        const int gslot = slot ^ ((row >> 1) & 3);
        bsrc[q] = Wb + (size_t)row * DIN + gslot * 8;
    }

    // ---- fragment read offsets
    const int arow = lane & 15;
    const int akk  = lane >> 4;                    // 0..3
    const int aswz0 = (akk * 2 + 0) ^ (arow & 7);  // (row&7)==(arow&7) since 16|m*16
    const int aswz1 = (akk * 2 + 1) ^ (arow & 7);
    const int obase = w * 64 + arow;
    const int bswz  = akk ^ ((obase >> 1) & 3);
    const int boff  = obase * BK + bswz * 8;

    f32x4 acc[4][4] = {};

    auto stage = [&](int buf, int ktile) {
        const int ke = ktile * BK;  // element offset (floats for A, shorts for B)
#pragma unroll
        for (int q = 0; q < 2; ++q)
            gload_lds16(asrc[q] + ke, &As[buf][(q * 4 + w) * 256]);
#pragma unroll
        for (int q = 0; q < 4; ++q)
            gload_lds16(bsrc[q] + ke, &Bs[buf][(q * 4 + w) * 512]);
    };

    auto compute = [&](int buf) {
        bf16x8 af[4], bq[4];
#pragma unroll
        for (int n = 0; n < 4; ++n)
            bq[n] = *reinterpret_cast<const bf16x8*>(&Bs[buf][boff + n * 16 * BK]);
#pragma unroll
        for (int m = 0; m < 4; ++m) {
            const float* ab = &As[buf][(arow + m * 16) * BK];
            f32x4 lo = *reinterpret_cast<const f32x4*>(ab + aswz0 * 4);
            f32x4 hi = *reinterpret_cast<const f32x4*>(ab + aswz1 * 4);
            u32x4 pk;
            pk.x = f2bf2(lo[0], lo[1]);
            pk.y = f2bf2(lo[2], lo[3]);
            pk.z = f2bf2(hi[0], hi[1]);
            pk.w = f2bf2(hi[2], hi[3]);
            af[m] = __builtin_bit_cast(bf16x8, pk);
        }
#pragma unroll
        for (int m = 0; m < 4; ++m)
#pragma unroll
            for (int n = 0; n < 4; ++n)
                acc[m][n] = __builtin_amdgcn_mfma_f32_16x16x32_bf16(af[m], bq[n], acc[m][n], 0, 0, 0);
    };

    // ---- prologue: fill 2 ring slots (12 DMA insts/wave in flight)
    stage(0, 0);
    stage(1, 1);

    // ---- main loop: counted vmcnt, raw barriers (no drain), prefetch depth 2.
    // Per iter: wait stage kt (leave stage kt+1's 6 insts in flight) -> barrier ->
    // issue stage kt+2 -> compute kt. WAR on ring slot (kt+2)%3 is vs epoch kt-1
    // readers, separated by this barrier.
#pragma unroll
    for (int kt = 0; kt < KSTEPS; ++kt) {
        if (kt < KSTEPS - 1)
            asm volatile("s_waitcnt vmcnt(6)" ::: "memory");
        else
            asm volatile("s_waitcnt vmcnt(0)" ::: "memory");
        __builtin_amdgcn_sched_barrier(0);
        __builtin_amdgcn_s_barrier();
        __builtin_amdgcn_sched_barrier(0);
        if (kt + 2 < KSTEPS) stage((kt + 2) % 3, kt + 2);
        compute(kt % 3);
    }

    // ---- epilogue: D mapping col = lane&15, row = (lane>>4)*4 + j
    const float* bn = Bias + node * DOUT + bcol;
    float* outb = Out + (size_t)brow * OUTSTRIDE + node * DOUT + bcol;
#pragma unroll
    for (int n = 0; n < 4; ++n) {
        const int col = w * 64 + n * 16 + arow;
        const float bias = bn[col];
#pragma unroll
        for (int m = 0; m < 4; ++m) {
            const int r0 = m * 16 + akk * 4;
#pragma unroll
            for (int j = 0; j < 4; ++j)
                outb[(size_t)(r0 + j) * OUTSTRIDE + col] = acc[m][n][j] + bias;
        }
    }
}

extern "C" void kernel_launch(void* const* d_in, const int* in_sizes, int n_in,
                              void* d_out, int out_size, void* d_ws, size_t ws_size,
                              hipStream_t stream) {
    const float* x = (const float*)d_in[0];      // [2048, 64, 512]
    const float* W = (const float*)d_in[1];      // [64, 512, 512]
    const float* b = (const float*)d_in[2];      // [64, 512]
    float* out = (float*)d_out;                  // [2048, 64*512]
    unsigned short* Wt = (unsigned short*)d_ws;  // bf16 [64][512][512] = 33.5 MB

    wt_transpose_kernel<<<dim3(DIN / 32, DOUT / 32, NN), dim3(32, 8), 0, stream>>>(W, Wt);
    node_gemm_kernel<<<dim3(4096), dim3(256), 0, stream>>>(x, Wt, b, out);
}

// Round 5
// 202.421 us; speedup vs baseline: 1.3484x; 1.3484x over previous
//
#include <hip/hip_runtime.h>

// y[b, n*DOUT+o] = sum_i x[b,n,i] * W[n,i,o] + bias[n,o]
// B=2048, N=64, DIN=512, DOUT=512, fp32 in/out, bf16 MFMA (fp32 accum).
// R5: occupancy-first. 512-thread blocks (8 waves, 2x4), BM=128 BN=256 BK=32,
// 48KB LDS 2-buffer, 16 waves/CU. A reg-staged (fp32->bf16 cvt), B via
// global_load_lds(16). Unified XOR slot swizzle on both operands.

#define NN 64
#define DIN 512
#define DOUT 512
#define BM 128
#define BN 256
#define BK 32
#define KSTEPS (DIN / BK)         // 16
#define ROWSTRIDE (NN * DIN)
#define OUTSTRIDE (NN * DOUT)

typedef __bf16 bf16x8 __attribute__((ext_vector_type(8)));
typedef float f32x4 __attribute__((ext_vector_type(4)));

__device__ __forceinline__ unsigned short f2bf(float f) {
    return __builtin_bit_cast(unsigned short, (__bf16)f);  // RNE
}
__device__ __forceinline__ unsigned int f2bf2(float a, float b) {
    return (unsigned int)f2bf(a) | ((unsigned int)f2bf(b) << 16);
}

typedef const __attribute__((address_space(1))) unsigned int* gas1_t;
typedef __attribute__((address_space(3))) unsigned int* las3_t;
__device__ __forceinline__ void gload_lds16(const void* g, void* l) {
    // LDS dest = wave-uniform base + lane*16 (m104); global src per-lane.
    __builtin_amdgcn_global_load_lds((gas1_t)g, (las3_t)l, 16, 0, 0);
}

// ---- pre-pass: Wt[n][o][i] = bf16(W[n][i][o]) ----
__global__ void wt_transpose_kernel(const float* __restrict__ W,
                                    unsigned short* __restrict__ Wt) {
    __shared__ float tile[32][33];
    const int n  = blockIdx.z;
    const int i0 = blockIdx.x * 32;
    const int o0 = blockIdx.y * 32;
    const float* Wn = W + (size_t)n * DIN * DOUT;
    unsigned short* Wtn = Wt + (size_t)n * DIN * DOUT;
    const int tx = threadIdx.x, ty = threadIdx.y;
#pragma unroll
    for (int q = 0; q < 4; ++q)
        tile[ty + q * 8][tx] = Wn[(size_t)(i0 + ty + q * 8) * DOUT + (o0 + tx)];
    __syncthreads();
#pragma unroll
    for (int q = 0; q < 4; ++q)
        Wtn[(size_t)(o0 + ty + q * 8) * DIN + (i0 + tx)] = f2bf(tile[tx][ty + q * 8]);
}

// ---- main GEMM ----
__global__ __launch_bounds__(512, 4) void node_gemm_kernel(
    const float* __restrict__ X, const unsigned short* __restrict__ Wt,
    const float* __restrict__ Bias, float* __restrict__ Out) {
    // layout: [row][4 slots of 8 shorts], slot' = slot ^ ((row>>1)&3)
    __shared__ unsigned short As[2][BM * BK];   // 2 x 8 KB
    __shared__ unsigned short Bs[2][BN * BK];   // 2 x 16 KB

    // 2048 WGs, bijective XCD swizzle (2048 % 8 == 0); ntile-minor for x-panel L2 reuse
    const int bid = blockIdx.x;
    const int swz = (bid & 7) * 256 + (bid >> 3);
    const int node  = swz >> 5;
    const int rem   = swz & 31;
    const int mtile = rem >> 1;
    const int ntile = rem & 1;
    const int brow = mtile * BM;
    const int bcol = ntile * BN;

    const int tid  = threadIdx.x;
    const int lane = tid & 63;
    const int w    = tid >> 6;        // 0..7
    const int wm   = w >> 2;          // 0..1: rows wm*64..
    const int wn   = w & 3;           // 0..3: cols wn*64..

    const float* Xb = X + (size_t)brow * ROWSTRIDE + node * DIN;
    const unsigned short* Wb = Wt + (size_t)node * DIN * DOUT + (size_t)bcol * DIN;

    // A staging: thread t -> row a_r = t>>2 (0..127), slot a_s = t&3 (8 floats)
    const int a_r  = tid >> 2;
    const int a_s  = tid & 3;
    const int a_sw = a_s ^ ((a_r >> 1) & 3);
    const float* a_src = Xb + (size_t)a_r * ROWSTRIDE + a_s * 8;
    const int a_dst = a_r * BK + a_sw * 8;   // shorts

    // B staging via gload_lds: inst i = q*8+w covers rows 16i..16i+15
    const unsigned short* b_src[2];
    int b_dst[2];
#pragma unroll
    for (int q = 0; q < 2; ++q) {
        const int i = q * 8 + w;
        const int c = i * 16 + (lane >> 2);      // col (B-row)
        const int s = lane & 3;
        const int gs = s ^ ((c >> 1) & 3);       // inverse slot swizzle on source
        b_src[q] = Wb + (size_t)c * DIN + gs * 8;
        b_dst[q] = i * 512;                      // shorts (1KB per inst)
    }

    // fragment read offsets: kswz identical for A and B (m*16, n*16 are 0 mod 4 after >>1)
    const int arow = lane & 15;
    const int akk  = lane >> 4;
    const int kswz = akk ^ ((arow >> 1) & 3);
    const int afrag = (wm * 64 + arow) * BK + kswz * 8;
    const int bfrag = (wn * 64 + arow) * BK + kswz * 8;

    f32x4 acc[4][4] = {};
    float4 av0, av1;

    auto stageB = [&](int buf, int kt) {
#pragma unroll
        for (int q = 0; q < 2; ++q)
            gload_lds16(b_src[q] + kt * BK, &Bs[buf][b_dst[q]]);
    };
    auto loadA = [&](int kt) {
        const float* p = a_src + kt * BK;
        av0 = *reinterpret_cast<const float4*>(p);
        av1 = *reinterpret_cast<const float4*>(p + 4);
    };
    auto storeA = [&](int buf) {
        uint4 pk;
        pk.x = f2bf2(av0.x, av0.y);
        pk.y = f2bf2(av0.z, av0.w);
        pk.z = f2bf2(av1.x, av1.y);
        pk.w = f2bf2(av1.z, av1.w);
        *reinterpret_cast<uint4*>(&As[buf][a_dst]) = pk;
    };

    // prologue
    loadA(0);
    stageB(0, 0);
    storeA(0);
    __syncthreads();

    int buf = 0;
    for (int kt = 0; kt < KSTEPS; ++kt) {
        const bool more = (kt < KSTEPS - 1);
        if (more) {                    // issue next-tile loads before compute
            stageB(buf ^ 1, kt + 1);
            loadA(kt + 1);
        }
        bf16x8 af[4], bq[4];
#pragma unroll
        for (int m = 0; m < 4; ++m)
            af[m] = *reinterpret_cast<const bf16x8*>(&As[buf][afrag + m * 16 * BK]);
#pragma unroll
        for (int n = 0; n < 4; ++n)
            bq[n] = *reinterpret_cast<const bf16x8*>(&Bs[buf][bfrag + n * 16 * BK]);
#pragma unroll
        for (int m = 0; m < 4; ++m)
#pragma unroll
            for (int n = 0; n < 4; ++n)
                acc[m][n] = __builtin_amdgcn_mfma_f32_16x16x32_bf16(af[m], bq[n], acc[m][n], 0, 0, 0);
        if (more) storeA(buf ^ 1);     // cvt + LDS write after MFMA (hides HBM latency)
        __syncthreads();
        buf ^= 1;
    }

    // epilogue: D mapping col = lane&15, row = (lane>>4)*4 + j
    const float* bn = Bias + node * DOUT + bcol;
    float* outb = Out + (size_t)brow * OUTSTRIDE + node * DOUT + bcol;
#pragma unroll
    for (int n = 0; n < 4; ++n) {
        const int col = wn * 64 + n * 16 + arow;
        const float bias = bn[col];
#pragma unroll
        for (int m = 0; m < 4; ++m) {
            const int r0 = wm * 64 + m * 16 + akk * 4;
#pragma unroll
            for (int j = 0; j < 4; ++j)
                outb[(size_t)(r0 + j) * OUTSTRIDE + col] = acc[m][n][j] + bias;
        }
    }
}

extern "C" void kernel_launch(void* const* d_in, const int* in_sizes, int n_in,
                              void* d_out, int out_size, void* d_ws, size_t ws_size,
                              hipStream_t stream) {
    const float* x = (const float*)d_in[0];      // [2048, 64, 512]
    const float* W = (const float*)d_in[1];      // [64, 512, 512]
    const float* b = (const float*)d_in[2];      // [64, 512]
    float* out = (float*)d_out;                  // [2048, 64*512]
    unsigned short* Wt = (unsigned short*)d_ws;  // bf16 [64][512][512] = 33.5 MB

    wt_transpose_kernel<<<dim3(DIN / 32, DOUT / 32, NN), dim3(32, 8), 0, stream>>>(W, Wt);
    node_gemm_kernel<<<dim3(2048), dim3(512), 0, stream>>>(x, Wt, b, out);
}